// Round 1
// 957.464 us; speedup vs baseline: 1.0264x; 1.0264x over previous
//
#include <hip/hip_runtime.h>
#include <math.h>

typedef __bf16 bf16_t;
typedef bf16_t bf16x8 __attribute__((ext_vector_type(8)));
typedef bf16_t bf16x2 __attribute__((ext_vector_type(2)));
typedef float f32x4 __attribute__((ext_vector_type(4)));

#define EMBED 2048
#define NHEADS 32
#define HDIM 64
#define MLP 8192
#define SEQ 1024
#define NTOK 2048      // B*S
#define QKV_N 6144

// async global->LDS, 16B per lane; LDS dest = wave-uniform base + lane*16
__device__ __forceinline__ void async_copy16(void* lds, const void* g) {
    __builtin_amdgcn_global_load_lds(
        (const __attribute__((address_space(1))) unsigned int*)g,
        (__attribute__((address_space(3))) unsigned int*)lds, 16, 0, 0);
}

// ---- DPP 16-lane (row) reductions: pure VALU, no LDS pipe ----
template<int CTRL>
__device__ __forceinline__ float dpp_f(float x) {
    return __int_as_float(__builtin_amdgcn_update_dpp(
        __float_as_int(x), __float_as_int(x), CTRL, 0xF, 0xF, false));
}
// row_ror:N = 0x120+N ; rotation folding gives ALL 16 lanes the result
__device__ __forceinline__ float rowmax16(float v) {
    v = fmaxf(v, dpp_f<0x121>(v));
    v = fmaxf(v, dpp_f<0x122>(v));
    v = fmaxf(v, dpp_f<0x124>(v));
    v = fmaxf(v, dpp_f<0x128>(v));
    return v;
}
__device__ __forceinline__ float rowsum16(float v) {
    v += dpp_f<0x121>(v);
    v += dpp_f<0x122>(v);
    v += dpp_f<0x124>(v);
    v += dpp_f<0x128>(v);
    return v;
}

// ---------------------------------------------------------------------------
// C = A(MxK,bf16) @ Bt(NxK,bf16)^T   (both with row stride LDK; K = per-split
// K-length, split index = blockIdx.z, k-range [z*K, z*K+K))
// EPI=0: bf16 store | EPI=1: fp32 store acc+Res | EPI=2: bf16 silu(Aux)*acc
// EPI=3: fp32 atomicAdd (split-K partial accumulate; Cout pre-initialized)
// 128x128 tile, BK=32, 4 waves, 16x16x32 bf16 MFMA (m97 structure)
// ---------------------------------------------------------------------------
template<int EPI>
__global__ __launch_bounds__(256) void gemm_bt(
    const bf16_t* __restrict__ A, const bf16_t* __restrict__ Bt,
    void* __restrict__ Cout, const float* __restrict__ Res,
    const bf16_t* __restrict__ Aux,
    int M, int N, int K, int LDK)
{
    __shared__ __align__(16) bf16_t As[128 * 32];
    __shared__ __align__(16) bf16_t Bs[128 * 32];
    const int tid = threadIdx.x;
    const int wave = tid >> 6, lane = tid & 63;
    const int quad = lane >> 4, l15 = lane & 15;
    const int wr = wave >> 1, wc = wave & 1;
    const int m0 = blockIdx.x * 128, n0 = blockIdx.y * 128;
    const int kbeg = blockIdx.z * K;
    const int srow = lane >> 2;
    const int scol = (lane & 3) * 8;

    f32x4 acc[4][4] = {};

    for (int kk = 0; kk < K; kk += 32) {
        const int k0 = kbeg + kk;
        if (kk) __syncthreads();
#pragma unroll
        for (int s = 0; s < 2; ++s) {
            const int chunk = wave * 2 + s;
            const int row = chunk * 16 + srow;
            async_copy16((char*)As + chunk * 1024,
                         A + (size_t)(m0 + row) * LDK + k0 + scol);
            async_copy16((char*)Bs + chunk * 1024,
                         Bt + (size_t)(n0 + row) * LDK + k0 + scol);
        }
        asm volatile("s_waitcnt vmcnt(0)" ::: "memory");
        __syncthreads();

        bf16x8 af[4], bfr[4];
#pragma unroll
        for (int i = 0; i < 4; ++i) {
            af[i]  = *(const bf16x8*)((const char*)As + (wr * 64 + i * 16 + l15) * 64 + quad * 16);
            bfr[i] = *(const bf16x8*)((const char*)Bs + (wc * 64 + i * 16 + l15) * 64 + quad * 16);
        }
#pragma unroll
        for (int i = 0; i < 4; ++i)
#pragma unroll
            for (int j = 0; j < 4; ++j)
                acc[i][j] = __builtin_amdgcn_mfma_f32_16x16x32_bf16(af[i], bfr[j], acc[i][j], 0, 0, 0);
    }

#pragma unroll
    for (int i = 0; i < 4; ++i) {
#pragma unroll
        for (int j = 0; j < 4; ++j) {
#pragma unroll
            for (int r = 0; r < 4; ++r) {
                const int row = m0 + wr * 64 + i * 16 + quad * 4 + r;
                const int col = n0 + wc * 64 + j * 16 + l15;
                const size_t idx = (size_t)row * N + col;
                if (EPI == 0) {
                    ((bf16_t*)Cout)[idx] = (bf16_t)acc[i][j][r];
                } else if (EPI == 1) {
                    ((float*)Cout)[idx] = Res[idx] + acc[i][j][r];
                } else if (EPI == 2) {
                    const float g = (float)Aux[idx];
                    const float s = g / (1.0f + __expf(-g));
                    ((bf16_t*)Cout)[idx] = (bf16_t)(s * acc[i][j][r]);
                } else {
                    // split-K partial: native fp32 atomic add (device scope,
                    // executed at memory-side coherent point -> L3 traffic)
                    unsafeAtomicAdd(&((float*)Cout)[idx], acc[i][j][r]);
                }
            }
        }
    }
}

// ---------------------------------------------------------------------------
// fp32 float4 copy (split-K output init with residual)
// ---------------------------------------------------------------------------
__global__ __launch_bounds__(256) void copy_f32(
    const float* __restrict__ src, float* __restrict__ dst)
{
    const int i = blockIdx.x * 256 + threadIdx.x;
    ((float4*)dst)[i] = ((const float4*)src)[i];
}

// ---------------------------------------------------------------------------
// W (KxN fp32) -> Wt (NxK bf16), 32x32 LDS tiles
// ---------------------------------------------------------------------------
__global__ __launch_bounds__(256) void transpose_cvt(
    const float* __restrict__ src, bf16_t* __restrict__ dst, int K, int N)
{
    __shared__ float tile[32][33];
    const int tx = threadIdx.x & 31, ty = threadIdx.x >> 5;
    const int n0 = blockIdx.x * 32, k0 = blockIdx.y * 32;
#pragma unroll
    for (int i = 0; i < 4; ++i)
        tile[ty + 8 * i][tx] = src[(size_t)(k0 + ty + 8 * i) * N + n0 + tx];
    __syncthreads();
#pragma unroll
    for (int i = 0; i < 4; ++i)
        dst[(size_t)(n0 + ty + 8 * i) * K + k0 + tx] = (bf16_t)tile[tx][ty + 8 * i];
}

// ---------------------------------------------------------------------------
// RMSNorm: fp32 row (2048) -> bf16 row
// ---------------------------------------------------------------------------
__global__ __launch_bounds__(256) void rmsnorm_bf16(
    const float* __restrict__ x, const float* __restrict__ g, bf16_t* __restrict__ out)
{
    const int row = blockIdx.x;
    const int tid = threadIdx.x;
    const float* xr = x + (size_t)row * EMBED + tid * 8;
    const float4 a = *(const float4*)xr;
    const float4 b = *(const float4*)(xr + 4);
    float ss = a.x * a.x + a.y * a.y + a.z * a.z + a.w * a.w
             + b.x * b.x + b.y * b.y + b.z * b.z + b.w * b.w;
#pragma unroll
    for (int off = 1; off < 64; off <<= 1) ss += __shfl_xor(ss, off);
    __shared__ float red[4];
    if ((tid & 63) == 0) red[tid >> 6] = ss;
    __syncthreads();
    const float rs = rsqrtf((red[0] + red[1] + red[2] + red[3]) * (1.0f / EMBED) + 1e-5f);
    const float* gr = g + tid * 8;
    const float xv[8] = {a.x, a.y, a.z, a.w, b.x, b.y, b.z, b.w};
    bf16x8 o;
#pragma unroll
    for (int e = 0; e < 8; ++e) o[e] = (bf16_t)(xv[e] * rs * gr[e]);
    *(bf16x8*)(out + (size_t)row * EMBED + tid * 8) = o;
}

// ---------------------------------------------------------------------------
// qkv [tok][6144] -> head-major Qh,Kh [(b*32+h)][s][64], RoPE.
// Q additionally scaled by 0.125 (exact) so attention skips the scale.
// ---------------------------------------------------------------------------
__global__ __launch_bounds__(256) void rope_transpose(
    const bf16_t* __restrict__ qkv, bf16_t* __restrict__ Qh, bf16_t* __restrict__ Kh)
{
    const int id = blockIdx.x * 256 + threadIdx.x;   // 0..65535
    const int tok = id >> 5;
    const int h = id & 31;
    const int s = tok & (SEQ - 1);
    const int bh = (tok >> 10) * NHEADS + h;
    const size_t dst = ((size_t)bh * SEQ + s) * HDIM;

    const bf16_t* q = qkv + (size_t)tok * QKV_N + h * HDIM;
    const bf16_t* k = q + EMBED;

    const bf16x2* qp = (const bf16x2*)q;
    const bf16x2* kp = (const bf16x2*)k;
    bf16x2* qo = (bf16x2*)(Qh + dst);
    bf16x2* ko = (bf16x2*)(Kh + dst);
    for (int i = 0; i < 32; ++i) {
        // 1/theta^(i/32) = exp2(-i*log2(5e5)/32)
        const float inv = exp2f((float)i * -0.59161151779f);
        const float ang = (float)s * inv;
        float sn, cs;
        sincosf(ang, &sn, &cs);
        bf16x2 qv = qp[i], kv = kp[i];
        const float q0 = (float)qv[0], q1 = (float)qv[1];
        const float k0 = (float)kv[0], k1 = (float)kv[1];
        qv[0] = (bf16_t)((q0 * cs - q1 * sn) * 0.125f);
        qv[1] = (bf16_t)((q0 * sn + q1 * cs) * 0.125f);
        kv[0] = (bf16_t)(k0 * cs - k1 * sn);
        kv[1] = (bf16_t)(k0 * sn + k1 * cs);
        qo[i] = qv; ko[i] = kv;
    }
}

// ---------------------------------------------------------------------------
// V transpose: qkv v-section -> Vt[(b*32+h)][dim][seq]
// grid (32 s-tiles, 64 bh), 256 threads
// ---------------------------------------------------------------------------
__global__ __launch_bounds__(256) void transpose_v(
    const bf16_t* __restrict__ qkv, bf16_t* __restrict__ Vt)
{
    __shared__ bf16_t tile[32][66];
    const int st = blockIdx.x;       // seq tile (32 rows)
    const int bh = blockIdx.y;
    const int b = bh >> 5, h = bh & 31;
    const int tid = threadIdx.x;

    const int d = tid & 63, sr = tid >> 6;
    const bf16_t* src = qkv + (size_t)(b * SEQ + st * 32) * QKV_N + 2 * EMBED + h * HDIM;
#pragma unroll
    for (int i = 0; i < 8; ++i) {
        const int s = i * 4 + sr;
        tile[s][d] = src[(size_t)s * QKV_N + d];
    }
    __syncthreads();
    const int s2 = tid & 31, dr = tid >> 5;
    bf16_t* dstp = Vt + (size_t)bh * HDIM * SEQ + st * 32;
#pragma unroll
    for (int i = 0; i < 8; ++i) {
        const int dd = i * 8 + dr;
        dstp[(size_t)dd * SEQ + s2] = tile[s2][dd];
    }
}

// ---------------------------------------------------------------------------
// Tile-sparse attention v4. Block=(qg,h,b), 4 waves; wave owns qt=wave*16+qg
// (balanced). DPP row reductions (no LDS shuffles). PV B-frags direct from
// global V^T. P transposed C->A layout via small LDS buffer.
// ---------------------------------------------------------------------------
__global__ __launch_bounds__(256, 4) void attn_sparse(
    const bf16_t* __restrict__ Qh, const bf16_t* __restrict__ Kh,
    const bf16_t* __restrict__ Vt, bf16_t* __restrict__ attn)
{
    const int qg = blockIdx.x;       // 0..15
    const int h  = blockIdx.y;
    const int b  = blockIdx.z;
    const int tid  = threadIdx.x;
    const int wave = tid >> 6, lane = tid & 63;
    const int quad = lane >> 4, l15 = lane & 15;
    const int qt = wave * 16 + qg;   // 0..63, block work sum ~constant

    __shared__ __align__(16) float  tilemax[4][16][68];
    __shared__ __align__(16) bf16_t Plds[4][16][40];
    __shared__ unsigned long long qmask[4][16];

    const size_t hoff = (size_t)(b * NHEADS + h) * SEQ * HDIM;
    const bf16_t* Qb  = Qh + hoff;
    const bf16_t* Kb  = Kh + hoff;
    const bf16_t* Vtb = Vt + hoff;   // [64][1024]

    const bf16_t* qrow = Qb + (size_t)(qt * 16 + l15) * HDIM;
    const bf16x8 qf0 = *(const bf16x8*)(qrow + quad * 8);
    const bf16x8 qf1 = *(const bf16x8*)(qrow + 32 + quad * 8);

    // ---- pass 1: tile maxima (DPP reduce, 1-ahead prefetch) ----
    const bf16_t* kbase = Kb + (size_t)l15 * HDIM + quad * 8;
    bf16x8 kc0 = *(const bf16x8*)(kbase);
    bf16x8 kc1 = *(const bf16x8*)(kbase + 32);
    for (int t = 0; t <= qt; ++t) {
        const bf16_t* knp = kbase + (size_t)((t < qt) ? t + 1 : t) * (16 * HDIM);
        const bf16x8 kn0 = *(const bf16x8*)(knp);
        const bf16x8 kn1 = *(const bf16x8*)(knp + 32);
        f32x4 sc = {0.f, 0.f, 0.f, 0.f};
        sc = __builtin_amdgcn_mfma_f32_16x16x32_bf16(qf0, kc0, sc, 0, 0, 0);
        sc = __builtin_amdgcn_mfma_f32_16x16x32_bf16(qf1, kc1, sc, 0, 0, 0);
#pragma unroll
        for (int r = 0; r < 4; ++r) {
            const int qr = quad * 4 + r;
            float v = (t == qt && l15 > qr) ? -3.0e38f : sc[r];
            v = rowmax16(v);
            if (l15 == 0) tilemax[wave][qr][t] = v;
        }
        kc0 = kn0; kc1 = kn1;
    }
    asm volatile("s_waitcnt lgkmcnt(0)" ::: "memory");   // in-wave DS drain

    // ---- selection: top-12 (strict >, earliest on ties) + own ----
    if (lane < 16) {
        unsigned long long m = 0;
        const int cnt = qt + 1;
        if (cnt <= 12) {
            m = (1ull << cnt) - 1ull;
        } else {
            const float* tmrow = &tilemax[wave][lane][0];
            const int c4 = qt >> 2;
            for (int it = 0; it < 12; ++it) {
                float best = -3.9e38f; int bi = 0;
                for (int c = 0; c <= c4; ++c) {
                    const float4 v4 = *(const float4*)(tmrow + c * 4);
                    const int tb = c * 4;
                    if (tb + 0 <= qt && !((m >> (tb + 0)) & 1ull) && v4.x > best) { best = v4.x; bi = tb + 0; }
                    if (tb + 1 <= qt && !((m >> (tb + 1)) & 1ull) && v4.y > best) { best = v4.y; bi = tb + 1; }
                    if (tb + 2 <= qt && !((m >> (tb + 2)) & 1ull) && v4.z > best) { best = v4.z; bi = tb + 2; }
                    if (tb + 3 <= qt && !((m >> (tb + 3)) & 1ull) && v4.w > best) { best = v4.w; bi = tb + 3; }
                }
                m |= 1ull << bi;
            }
        }
        m |= 1ull << qt;
        qmask[wave][lane] = m;
    }
    asm volatile("s_waitcnt lgkmcnt(0)" ::: "memory");

    unsigned long long un = 0;
#pragma unroll
    for (int i = 0; i < 16; ++i) un |= qmask[wave][i];
    unsigned long long myrow[4];
#pragma unroll
    for (int r = 0; r < 4; ++r) myrow[r] = qmask[wave][quad * 4 + r];

    float m_run[4], l_run[4];
#pragma unroll
    for (int r = 0; r < 4; ++r) { m_run[r] = -3.0e38f; l_run[r] = 0.f; }
    f32x4 o[4] = {};   // o[jb][r] = D[quad*4+r][jb*16+l15]

    // ---- pass 2: selected tiles in pairs, MFMA PV ----
    unsigned long long sel = un;
    while (sel) {
        const int t0 = (int)__builtin_ctzll(sel); sel &= sel - 1ull;
        int t1 = -1;
        if (sel) { t1 = (int)__builtin_ctzll(sel); sel &= sel - 1ull; }
        const int t1e = (t1 >= 0) ? t1 : t0;

        const bf16_t* kr0 = Kb + (size_t)(t0 * 16 + l15) * HDIM + quad * 8;
        const bf16x8 k00 = *(const bf16x8*)(kr0);
        const bf16x8 k01 = *(const bf16x8*)(kr0 + 32);
        const bf16_t* kr1 = Kb + (size_t)(t1e * 16 + l15) * HDIM + quad * 8;
        const bf16x8 k10 = *(const bf16x8*)(kr1);
        const bf16x8 k11 = *(const bf16x8*)(kr1 + 32);

        // B-frags from global V^T (keys: quad<2 -> t0, quad>=2 -> t1e)
        const int colb = ((quad < 2) ? t0 : t1e) * 16 + (quad & 1) * 8;
        bf16x8 vf[4];
#pragma unroll
        for (int jb = 0; jb < 4; ++jb)
            vf[jb] = *(const bf16x8*)(Vtb + (size_t)(jb * 16 + l15) * SEQ + colb);

        f32x4 s0 = {0.f, 0.f, 0.f, 0.f}, s1 = {0.f, 0.f, 0.f, 0.f};
        s0 = __builtin_amdgcn_mfma_f32_16x16x32_bf16(qf0, k00, s0, 0, 0, 0);
        s0 = __builtin_amdgcn_mfma_f32_16x16x32_bf16(qf1, k01, s0, 0, 0, 0);
        s1 = __builtin_amdgcn_mfma_f32_16x16x32_bf16(qf0, k10, s1, 0, 0, 0);
        s1 = __builtin_amdgcn_mfma_f32_16x16x32_bf16(qf1, k11, s1, 0, 0, 0);

#pragma unroll
        for (int r = 0; r < 4; ++r) {
            const int qr = quad * 4 + r;
            const bool ok0 = ((myrow[r] >> t0) & 1ull) && (t0 < qt || l15 <= qr);
            const bool ok1 = (t1 >= 0) && ((myrow[r] >> t1) & 1ull) && (t1 < qt || l15 <= qr);
            const float sv0 = ok0 ? s0[r] : -3.0e38f;
            const float sv1 = ok1 ? s1[r] : -3.0e38f;
            const float mt = rowmax16(fmaxf(sv0, sv1));
            const float mn = fmaxf(m_run[r], mt);
            const float al = __expf(m_run[r] - mn);
            const float p0 = ok0 ? __expf(sv0 - mn) : 0.f;
            const float p1 = ok1 ? __expf(sv1 - mn) : 0.f;
            const float rsum = rowsum16(p0 + p1);
            l_run[r] = l_run[r] * al + rsum;
            m_run[r] = mn;
            Plds[wave][qr][l15]      = (bf16_t)p0;
            Plds[wave][qr][16 + l15] = (bf16_t)p1;
#pragma unroll
            for (int jb = 0; jb < 4; ++jb) o[jb][r] *= al;
        }
        asm volatile("s_waitcnt lgkmcnt(0)" ::: "memory");

        const bf16x8 pa = *(const bf16x8*)&Plds[wave][l15][quad * 8];
#pragma unroll
        for (int jb = 0; jb < 4; ++jb)
            o[jb] = __builtin_amdgcn_mfma_f32_16x16x32_bf16(pa, vf[jb], o[jb], 0, 0, 0);
    }

    // ---- epilogue: normalize, store ----
    const int tok0 = b * SEQ + qt * 16;
#pragma unroll
    for (int r = 0; r < 4; ++r) {
        const int qr = quad * 4 + r;
        const float inv = 1.0f / l_run[r];
        bf16_t* op = attn + (size_t)(tok0 + qr) * EMBED + h * HDIM + l15;
#pragma unroll
        for (int jb = 0; jb < 4; ++jb)
            op[jb * 16] = (bf16_t)(o[jb][r] * inv);
    }
}

// ---------------------------------------------------------------------------
// Workspace layout (120 MB peak, lifetime-overlaid):
//   [0,32M)     Wt region: wqkv_t(24M)/wo_t(8M)/wg_t(32M)/wu_t(32M)/wd_t(32M)
//   [32,56M)    qkv(24M)          -> later gate(32M) spans [32,64M)
//   [56,64M)    attnb(8M)
//   [64,80M)    x1 fp32(16M)
//   [80,88M)    nbuf/n2(8M)
//   [88,118M)   Qh/Kh/Vt(3x~10M)  -> later hbuf(32M) spans [88,120M)
// ---------------------------------------------------------------------------
extern "C" void kernel_launch(void* const* d_in, const int* in_sizes, int n_in,
                              void* d_out, int out_size, void* d_ws, size_t ws_size,
                              hipStream_t stream)
{
    const float* x   = (const float*)d_in[0];
    const float* ans = (const float*)d_in[1];
    const float* wq  = (const float*)d_in[2];
    const float* wk  = (const float*)d_in[3];
    const float* wv  = (const float*)d_in[4];
    const float* wo  = (const float*)d_in[5];
    const float* fns = (const float*)d_in[6];
    const float* wg  = (const float*)d_in[7];
    const float* wu  = (const float*)d_in[8];
    const float* wd  = (const float*)d_in[9];
    (void)in_sizes; (void)n_in; (void)out_size; (void)ws_size;

    char* ws = (char*)d_ws;
    const size_t MB = 1024 * 1024;
    bf16_t* wt_reg = (bf16_t*)(ws);             // 32 MB weight region
    bf16_t* qkv    = (bf16_t*)(ws + 32 * MB);   // 24 MB
    bf16_t* attnb  = (bf16_t*)(ws + 56 * MB);   // 8 MB
    bf16_t* gate   = (bf16_t*)(ws + 32 * MB);   // 32 MB (overlays dead qkv+attnb)
    float*  x1     = (float* )(ws + 64 * MB);   // 16 MB
    bf16_t* nbuf   = (bf16_t*)(ws + 80 * MB);   // 8 MB (also n2)
    bf16_t* Qh     = (bf16_t*)(ws + 88 * MB);   // 8.4 MB
    bf16_t* Kh     = (bf16_t*)(ws + 98 * MB);   // 8.4 MB
    bf16_t* Vt     = (bf16_t*)(ws + 108 * MB);  // 8.4 MB (transposed V)
    bf16_t* hbuf   = (bf16_t*)(ws + 88 * MB);   // 32 MB (overlays dead Qh/Kh/Vt)

    // ---- attention phase ----
    transpose_cvt<<<dim3(64, 64), 256, 0, stream>>>(wq, wt_reg,                             EMBED, EMBED);
    transpose_cvt<<<dim3(64, 64), 256, 0, stream>>>(wk, wt_reg + (size_t)EMBED * EMBED,     EMBED, EMBED);
    transpose_cvt<<<dim3(64, 64), 256, 0, stream>>>(wv, wt_reg + (size_t)2 * EMBED * EMBED, EMBED, EMBED);
    rmsnorm_bf16<<<NTOK, 256, 0, stream>>>(x, ans, nbuf);
    gemm_bt<0><<<dim3(16, 48), 256, 0, stream>>>(nbuf, wt_reg, qkv, nullptr, nullptr, NTOK, QKV_N, EMBED, EMBED);
    rope_transpose<<<256, 256, 0, stream>>>(qkv, Qh, Kh);
    transpose_v<<<dim3(32, 64), 256, 0, stream>>>(qkv, Vt);
    attn_sparse<<<dim3(16, 32, 2), 256, 0, stream>>>(Qh, Kh, Vt, attnb);
    transpose_cvt<<<dim3(64, 64), 256, 0, stream>>>(wo, wt_reg, EMBED, EMBED);   // wqkv_t dead
    // attn-out GEMM: split-K=2 (512 blocks = 2/CU), x1 pre-init with residual x
    copy_f32<<<4096, 256, 0, stream>>>(x, x1);
    gemm_bt<3><<<dim3(16, 16, 2), 256, 0, stream>>>(attnb, wt_reg, x1, nullptr, nullptr, NTOK, EMBED, EMBED / 2, EMBED);

    // ---- MLP phase ----
    rmsnorm_bf16<<<NTOK, 256, 0, stream>>>(x1, fns, nbuf);                       // n2
    transpose_cvt<<<dim3(256, 64), 256, 0, stream>>>(wg, wt_reg, EMBED, MLP);    // wo_t dead
    gemm_bt<0><<<dim3(16, 64), 256, 0, stream>>>(nbuf, wt_reg, gate, nullptr, nullptr, NTOK, MLP, EMBED, EMBED);
    transpose_cvt<<<dim3(256, 64), 256, 0, stream>>>(wu, wt_reg, EMBED, MLP);    // wg_t dead
    gemm_bt<2><<<dim3(16, 64), 256, 0, stream>>>(nbuf, wt_reg, hbuf, nullptr, gate, NTOK, MLP, EMBED, EMBED);
    transpose_cvt<<<dim3(64, 256), 256, 0, stream>>>(wd, wt_reg, MLP, EMBED);    // wu_t dead
    // down GEMM: split-K=4 (1024 blocks = 4/CU), d_out pre-init with residual x1
    copy_f32<<<4096, 256, 0, stream>>>(x1, (float*)d_out);
    gemm_bt<3><<<dim3(16, 16, 4), 256, 0, stream>>>(hbuf, wt_reg, (float*)d_out, nullptr, nullptr, NTOK, EMBED, MLP / 4, MLP);
}

// Round 2
// 924.447 us; speedup vs baseline: 1.0630x; 1.0357x over previous
//
#include <hip/hip_runtime.h>
#include <math.h>

typedef __bf16 bf16_t;
typedef bf16_t bf16x8 __attribute__((ext_vector_type(8)));
typedef bf16_t bf16x2 __attribute__((ext_vector_type(2)));
typedef float f32x4 __attribute__((ext_vector_type(4)));

#define EMBED 2048
#define NHEADS 32
#define HDIM 64
#define MLP 8192
#define SEQ 1024
#define NTOK 2048      // B*S
#define QKV_N 6144

// async global->LDS, 16B per lane; LDS dest = wave-uniform base + lane*16
__device__ __forceinline__ void async_copy16(void* lds, const void* g) {
    __builtin_amdgcn_global_load_lds(
        (const __attribute__((address_space(1))) unsigned int*)g,
        (__attribute__((address_space(3))) unsigned int*)lds, 16, 0, 0);
}

// ---- DPP 16-lane (row) reductions: pure VALU, no LDS pipe ----
template<int CTRL>
__device__ __forceinline__ float dpp_f(float x) {
    return __int_as_float(__builtin_amdgcn_update_dpp(
        __float_as_int(x), __float_as_int(x), CTRL, 0xF, 0xF, false));
}
// row_ror:N = 0x120+N ; rotation folding gives ALL 16 lanes the result
__device__ __forceinline__ float rowmax16(float v) {
    v = fmaxf(v, dpp_f<0x121>(v));
    v = fmaxf(v, dpp_f<0x122>(v));
    v = fmaxf(v, dpp_f<0x124>(v));
    v = fmaxf(v, dpp_f<0x128>(v));
    return v;
}
__device__ __forceinline__ float rowsum16(float v) {
    v += dpp_f<0x121>(v);
    v += dpp_f<0x122>(v);
    v += dpp_f<0x124>(v);
    v += dpp_f<0x128>(v);
    return v;
}

// ---------------------------------------------------------------------------
// C = A(MxK,bf16) @ Bt(NxK,bf16)^T   (both with row stride LDK; K = per-split
// K-length, split index = blockIdx.z, k-range [z*K, z*K+K))
// EPI=0: bf16 store | EPI=1: fp32 store acc+Res | EPI=2: bf16 silu(Aux)*acc
// EPI=3: fp32 atomicAdd (split-K partial accumulate; Cout pre-initialized)
// 128x128 tile, BK=32, 4 waves, 16x16x32 bf16 MFMA (m97 structure)
// ---------------------------------------------------------------------------
template<int EPI>
__global__ __launch_bounds__(256) void gemm_bt(
    const bf16_t* __restrict__ A, const bf16_t* __restrict__ Bt,
    void* __restrict__ Cout, const float* __restrict__ Res,
    const bf16_t* __restrict__ Aux,
    int M, int N, int K, int LDK)
{
    __shared__ __align__(16) bf16_t As[128 * 32];
    __shared__ __align__(16) bf16_t Bs[128 * 32];
    const int tid = threadIdx.x;
    const int wave = tid >> 6, lane = tid & 63;
    const int quad = lane >> 4, l15 = lane & 15;
    const int wr = wave >> 1, wc = wave & 1;
    const int m0 = blockIdx.x * 128, n0 = blockIdx.y * 128;
    const int kbeg = blockIdx.z * K;
    const int srow = lane >> 2;
    const int scol = (lane & 3) * 8;

    f32x4 acc[4][4] = {};

    for (int kk = 0; kk < K; kk += 32) {
        const int k0 = kbeg + kk;
        if (kk) __syncthreads();
#pragma unroll
        for (int s = 0; s < 2; ++s) {
            const int chunk = wave * 2 + s;
            const int row = chunk * 16 + srow;
            async_copy16((char*)As + chunk * 1024,
                         A + (size_t)(m0 + row) * LDK + k0 + scol);
            async_copy16((char*)Bs + chunk * 1024,
                         Bt + (size_t)(n0 + row) * LDK + k0 + scol);
        }
        asm volatile("s_waitcnt vmcnt(0)" ::: "memory");
        __syncthreads();

        bf16x8 af[4], bfr[4];
#pragma unroll
        for (int i = 0; i < 4; ++i) {
            af[i]  = *(const bf16x8*)((const char*)As + (wr * 64 + i * 16 + l15) * 64 + quad * 16);
            bfr[i] = *(const bf16x8*)((const char*)Bs + (wc * 64 + i * 16 + l15) * 64 + quad * 16);
        }
#pragma unroll
        for (int i = 0; i < 4; ++i)
#pragma unroll
            for (int j = 0; j < 4; ++j)
                acc[i][j] = __builtin_amdgcn_mfma_f32_16x16x32_bf16(af[i], bfr[j], acc[i][j], 0, 0, 0);
    }

#pragma unroll
    for (int i = 0; i < 4; ++i) {
#pragma unroll
        for (int j = 0; j < 4; ++j) {
#pragma unroll
            for (int r = 0; r < 4; ++r) {
                const int row = m0 + wr * 64 + i * 16 + quad * 4 + r;
                const int col = n0 + wc * 64 + j * 16 + l15;
                const size_t idx = (size_t)row * N + col;
                if (EPI == 0) {
                    ((bf16_t*)Cout)[idx] = (bf16_t)acc[i][j][r];
                } else if (EPI == 1) {
                    ((float*)Cout)[idx] = Res[idx] + acc[i][j][r];
                } else if (EPI == 2) {
                    const float g = (float)Aux[idx];
                    const float s = g / (1.0f + __expf(-g));
                    ((bf16_t*)Cout)[idx] = (bf16_t)(s * acc[i][j][r]);
                } else {
                    // split-K partial: native fp32 atomic add (device scope,
                    // executed at memory-side coherent point -> L3 traffic)
                    unsafeAtomicAdd(&((float*)Cout)[idx], acc[i][j][r]);
                }
            }
        }
    }
}

// ---------------------------------------------------------------------------
// fp32 float4 copy (split-K output init with residual)
// ---------------------------------------------------------------------------
__global__ __launch_bounds__(256) void copy_f32(
    const float* __restrict__ src, float* __restrict__ dst)
{
    const int i = blockIdx.x * 256 + threadIdx.x;
    ((float4*)dst)[i] = ((const float4*)src)[i];
}

// ---------------------------------------------------------------------------
// W (KxN fp32) -> Wt (NxK bf16), 32x32 LDS tiles
// ---------------------------------------------------------------------------
__global__ __launch_bounds__(256) void transpose_cvt(
    const float* __restrict__ src, bf16_t* __restrict__ dst, int K, int N)
{
    __shared__ float tile[32][33];
    const int tx = threadIdx.x & 31, ty = threadIdx.x >> 5;
    const int n0 = blockIdx.x * 32, k0 = blockIdx.y * 32;
#pragma unroll
    for (int i = 0; i < 4; ++i)
        tile[ty + 8 * i][tx] = src[(size_t)(k0 + ty + 8 * i) * N + n0 + tx];
    __syncthreads();
#pragma unroll
    for (int i = 0; i < 4; ++i)
        dst[(size_t)(n0 + ty + 8 * i) * K + k0 + tx] = (bf16_t)tile[tx][ty + 8 * i];
}

// ---------------------------------------------------------------------------
// RMSNorm: fp32 row (2048) -> bf16 row
// ---------------------------------------------------------------------------
__global__ __launch_bounds__(256) void rmsnorm_bf16(
    const float* __restrict__ x, const float* __restrict__ g, bf16_t* __restrict__ out)
{
    const int row = blockIdx.x;
    const int tid = threadIdx.x;
    const float* xr = x + (size_t)row * EMBED + tid * 8;
    const float4 a = *(const float4*)xr;
    const float4 b = *(const float4*)(xr + 4);
    float ss = a.x * a.x + a.y * a.y + a.z * a.z + a.w * a.w
             + b.x * b.x + b.y * b.y + b.z * b.z + b.w * b.w;
#pragma unroll
    for (int off = 1; off < 64; off <<= 1) ss += __shfl_xor(ss, off);
    __shared__ float red[4];
    if ((tid & 63) == 0) red[tid >> 6] = ss;
    __syncthreads();
    const float rs = rsqrtf((red[0] + red[1] + red[2] + red[3]) * (1.0f / EMBED) + 1e-5f);
    const float* gr = g + tid * 8;
    const float xv[8] = {a.x, a.y, a.z, a.w, b.x, b.y, b.z, b.w};
    bf16x8 o;
#pragma unroll
    for (int e = 0; e < 8; ++e) o[e] = (bf16_t)(xv[e] * rs * gr[e]);
    *(bf16x8*)(out + (size_t)row * EMBED + tid * 8) = o;
}

// ---------------------------------------------------------------------------
// qkv [tok][6144] -> head-major Qh,Kh [(b*32+h)][s][64], RoPE.
// Q additionally scaled by 0.125 (exact) so attention skips the scale.
// ---------------------------------------------------------------------------
__global__ __launch_bounds__(256) void rope_transpose(
    const bf16_t* __restrict__ qkv, bf16_t* __restrict__ Qh, bf16_t* __restrict__ Kh)
{
    const int id = blockIdx.x * 256 + threadIdx.x;   // 0..65535
    const int tok = id >> 5;
    const int h = id & 31;
    const int s = tok & (SEQ - 1);
    const int bh = (tok >> 10) * NHEADS + h;
    const size_t dst = ((size_t)bh * SEQ + s) * HDIM;

    const bf16_t* q = qkv + (size_t)tok * QKV_N + h * HDIM;
    const bf16_t* k = q + EMBED;

    const bf16x2* qp = (const bf16x2*)q;
    const bf16x2* kp = (const bf16x2*)k;
    bf16x2* qo = (bf16x2*)(Qh + dst);
    bf16x2* ko = (bf16x2*)(Kh + dst);
    for (int i = 0; i < 32; ++i) {
        // 1/theta^(i/32) = exp2(-i*log2(5e5)/32)
        const float inv = exp2f((float)i * -0.59161151779f);
        const float ang = (float)s * inv;
        float sn, cs;
        sincosf(ang, &sn, &cs);
        bf16x2 qv = qp[i], kv = kp[i];
        const float q0 = (float)qv[0], q1 = (float)qv[1];
        const float k0 = (float)kv[0], k1 = (float)kv[1];
        qv[0] = (bf16_t)((q0 * cs - q1 * sn) * 0.125f);
        qv[1] = (bf16_t)((q0 * sn + q1 * cs) * 0.125f);
        kv[0] = (bf16_t)(k0 * cs - k1 * sn);
        kv[1] = (bf16_t)(k0 * sn + k1 * cs);
        qo[i] = qv; ko[i] = kv;
    }
}

// ---------------------------------------------------------------------------
// V transpose: qkv v-section -> Vt[(b*32+h)][dim][seq]
// grid (32 s-tiles, 64 bh), 256 threads
// ---------------------------------------------------------------------------
__global__ __launch_bounds__(256) void transpose_v(
    const bf16_t* __restrict__ qkv, bf16_t* __restrict__ Vt)
{
    __shared__ bf16_t tile[32][66];
    const int st = blockIdx.x;       // seq tile (32 rows)
    const int bh = blockIdx.y;
    const int b = bh >> 5, h = bh & 31;
    const int tid = threadIdx.x;

    const int d = tid & 63, sr = tid >> 6;
    const bf16_t* src = qkv + (size_t)(b * SEQ + st * 32) * QKV_N + 2 * EMBED + h * HDIM;
#pragma unroll
    for (int i = 0; i < 8; ++i) {
        const int s = i * 4 + sr;
        tile[s][d] = src[(size_t)s * QKV_N + d];
    }
    __syncthreads();
    const int s2 = tid & 31, dr = tid >> 5;
    bf16_t* dstp = Vt + (size_t)bh * HDIM * SEQ + st * 32;
#pragma unroll
    for (int i = 0; i < 8; ++i) {
        const int dd = i * 8 + dr;
        dstp[(size_t)dd * SEQ + s2] = tile[s2][dd];
    }
}

// ---------------------------------------------------------------------------
// Tile-sparse attention v5. 1-D grid of 1024, XCD-colocating decode:
//   x = id&7 (XCD), j = id>>3; qg = j&15, hb = (j>>4)*8 + x
// -> all 16 qg blocks of one head land on ONE XCD (L2 working set
//    ~4 heads x 384 KB ~= 1.5 MB < 4 MB), vs round-robin thrash before.
// Wave->qt map {qg, 31-qg, 32+qg, 63-qg}: per-block pass-1 work constant
// (130 tile-units) -> no ragged tail.
// ---------------------------------------------------------------------------
__global__ __launch_bounds__(256, 4) void attn_sparse(
    const bf16_t* __restrict__ Qh, const bf16_t* __restrict__ Kh,
    const bf16_t* __restrict__ Vt, bf16_t* __restrict__ attn)
{
    const int id = blockIdx.x;
    const int xcd = id & 7;
    const int j = id >> 3;
    const int qg = j & 15;           // 0..15
    const int hb = (j >> 4) * 8 + xcd;
    const int h = hb & 31;
    const int b = hb >> 5;
    const int tid  = threadIdx.x;
    const int wave = tid >> 6, lane = tid & 63;
    const int quad = lane >> 4, l15 = lane & 15;
    // balanced qt: {qg, 31-qg, 32+qg, 63-qg} -> block work sum constant
    const int qt = (wave & 1) ? (wave * 16 + 15 - qg) : (wave * 16 + qg);

    __shared__ __align__(16) float  tilemax[4][16][68];
    __shared__ __align__(16) bf16_t Plds[4][16][40];
    __shared__ unsigned long long qmask[4][16];

    const size_t hoff = (size_t)(b * NHEADS + h) * SEQ * HDIM;
    const bf16_t* Qb  = Qh + hoff;
    const bf16_t* Kb  = Kh + hoff;
    const bf16_t* Vtb = Vt + hoff;   // [64][1024]

    const bf16_t* qrow = Qb + (size_t)(qt * 16 + l15) * HDIM;
    const bf16x8 qf0 = *(const bf16x8*)(qrow + quad * 8);
    const bf16x8 qf1 = *(const bf16x8*)(qrow + 32 + quad * 8);

    // ---- pass 1: tile maxima (DPP reduce, 1-ahead prefetch) ----
    const bf16_t* kbase = Kb + (size_t)l15 * HDIM + quad * 8;
    bf16x8 kc0 = *(const bf16x8*)(kbase);
    bf16x8 kc1 = *(const bf16x8*)(kbase + 32);
    for (int t = 0; t <= qt; ++t) {
        const bf16_t* knp = kbase + (size_t)((t < qt) ? t + 1 : t) * (16 * HDIM);
        const bf16x8 kn0 = *(const bf16x8*)(knp);
        const bf16x8 kn1 = *(const bf16x8*)(knp + 32);
        f32x4 sc = {0.f, 0.f, 0.f, 0.f};
        sc = __builtin_amdgcn_mfma_f32_16x16x32_bf16(qf0, kc0, sc, 0, 0, 0);
        sc = __builtin_amdgcn_mfma_f32_16x16x32_bf16(qf1, kc1, sc, 0, 0, 0);
#pragma unroll
        for (int r = 0; r < 4; ++r) {
            const int qr = quad * 4 + r;
            float v = (t == qt && l15 > qr) ? -3.0e38f : sc[r];
            v = rowmax16(v);
            if (l15 == 0) tilemax[wave][qr][t] = v;
        }
        kc0 = kn0; kc1 = kn1;
    }
    asm volatile("s_waitcnt lgkmcnt(0)" ::: "memory");   // in-wave DS drain

    // ---- selection: top-12 (strict >, earliest on ties) + own ----
    if (lane < 16) {
        unsigned long long m = 0;
        const int cnt = qt + 1;
        if (cnt <= 12) {
            m = (1ull << cnt) - 1ull;
        } else {
            const float* tmrow = &tilemax[wave][lane][0];
            const int c4 = qt >> 2;
            for (int it = 0; it < 12; ++it) {
                float best = -3.9e38f; int bi = 0;
                for (int c = 0; c <= c4; ++c) {
                    const float4 v4 = *(const float4*)(tmrow + c * 4);
                    const int tb = c * 4;
                    if (tb + 0 <= qt && !((m >> (tb + 0)) & 1ull) && v4.x > best) { best = v4.x; bi = tb + 0; }
                    if (tb + 1 <= qt && !((m >> (tb + 1)) & 1ull) && v4.y > best) { best = v4.y; bi = tb + 1; }
                    if (tb + 2 <= qt && !((m >> (tb + 2)) & 1ull) && v4.z > best) { best = v4.z; bi = tb + 2; }
                    if (tb + 3 <= qt && !((m >> (tb + 3)) & 1ull) && v4.w > best) { best = v4.w; bi = tb + 3; }
                }
                m |= 1ull << bi;
            }
        }
        m |= 1ull << qt;
        qmask[wave][lane] = m;
    }
    asm volatile("s_waitcnt lgkmcnt(0)" ::: "memory");

    unsigned long long un = 0;
#pragma unroll
    for (int i = 0; i < 16; ++i) un |= qmask[wave][i];
    unsigned long long myrow[4];
#pragma unroll
    for (int r = 0; r < 4; ++r) myrow[r] = qmask[wave][quad * 4 + r];

    float m_run[4], l_run[4];
#pragma unroll
    for (int r = 0; r < 4; ++r) { m_run[r] = -3.0e38f; l_run[r] = 0.f; }
    f32x4 o[4] = {};   // o[jb][r] = D[quad*4+r][jb*16+l15]

    // ---- pass 2: selected tiles in pairs, MFMA PV ----
    unsigned long long sel = un;
    while (sel) {
        const int t0 = (int)__builtin_ctzll(sel); sel &= sel - 1ull;
        int t1 = -1;
        if (sel) { t1 = (int)__builtin_ctzll(sel); sel &= sel - 1ull; }
        const int t1e = (t1 >= 0) ? t1 : t0;

        const bf16_t* kr0 = Kb + (size_t)(t0 * 16 + l15) * HDIM + quad * 8;
        const bf16x8 k00 = *(const bf16x8*)(kr0);
        const bf16x8 k01 = *(const bf16x8*)(kr0 + 32);
        const bf16_t* kr1 = Kb + (size_t)(t1e * 16 + l15) * HDIM + quad * 8;
        const bf16x8 k10 = *(const bf16x8*)(kr1);
        const bf16x8 k11 = *(const bf16x8*)(kr1 + 32);

        // B-frags from global V^T (keys: quad<2 -> t0, quad>=2 -> t1e)
        const int colb = ((quad < 2) ? t0 : t1e) * 16 + (quad & 1) * 8;
        bf16x8 vf[4];
#pragma unroll
        for (int jb = 0; jb < 4; ++jb)
            vf[jb] = *(const bf16x8*)(Vtb + (size_t)(jb * 16 + l15) * SEQ + colb);

        f32x4 s0 = {0.f, 0.f, 0.f, 0.f}, s1 = {0.f, 0.f, 0.f, 0.f};
        s0 = __builtin_amdgcn_mfma_f32_16x16x32_bf16(qf0, k00, s0, 0, 0, 0);
        s0 = __builtin_amdgcn_mfma_f32_16x16x32_bf16(qf1, k01, s0, 0, 0, 0);
        s1 = __builtin_amdgcn_mfma_f32_16x16x32_bf16(qf0, k10, s1, 0, 0, 0);
        s1 = __builtin_amdgcn_mfma_f32_16x16x32_bf16(qf1, k11, s1, 0, 0, 0);

#pragma unroll
        for (int r = 0; r < 4; ++r) {
            const int qr = quad * 4 + r;
            const bool ok0 = ((myrow[r] >> t0) & 1ull) && (t0 < qt || l15 <= qr);
            const bool ok1 = (t1 >= 0) && ((myrow[r] >> t1) & 1ull) && (t1 < qt || l15 <= qr);
            const float sv0 = ok0 ? s0[r] : -3.0e38f;
            const float sv1 = ok1 ? s1[r] : -3.0e38f;
            const float mt = rowmax16(fmaxf(sv0, sv1));
            const float mn = fmaxf(m_run[r], mt);
            const float al = __expf(m_run[r] - mn);
            const float p0 = ok0 ? __expf(sv0 - mn) : 0.f;
            const float p1 = ok1 ? __expf(sv1 - mn) : 0.f;
            const float rsum = rowsum16(p0 + p1);
            l_run[r] = l_run[r] * al + rsum;
            m_run[r] = mn;
            Plds[wave][qr][l15]      = (bf16_t)p0;
            Plds[wave][qr][16 + l15] = (bf16_t)p1;
#pragma unroll
            for (int jb = 0; jb < 4; ++jb) o[jb][r] *= al;
        }
        asm volatile("s_waitcnt lgkmcnt(0)" ::: "memory");

        const bf16x8 pa = *(const bf16x8*)&Plds[wave][l15][quad * 8];
#pragma unroll
        for (int jb = 0; jb < 4; ++jb)
            o[jb] = __builtin_amdgcn_mfma_f32_16x16x32_bf16(pa, vf[jb], o[jb], 0, 0, 0);
    }

    // ---- epilogue: normalize, store ----
    const int tok0 = b * SEQ + qt * 16;
#pragma unroll
    for (int r = 0; r < 4; ++r) {
        const int qr = quad * 4 + r;
        const float inv = 1.0f / l_run[r];
        bf16_t* op = attn + (size_t)(tok0 + qr) * EMBED + h * HDIM + l15;
#pragma unroll
        for (int jb = 0; jb < 4; ++jb)
            op[jb * 16] = (bf16_t)(o[jb][r] * inv);
    }
}

// ---------------------------------------------------------------------------
// Workspace layout (120 MB peak, lifetime-overlaid):
//   [0,32M)     Wt region: wqkv_t(24M)/wo_t(8M)/wg_t(32M)/wu_t(32M)/wd_t(32M)
//   [32,56M)    qkv(24M)          -> later gate(32M) spans [32,64M)
//   [56,64M)    attnb(8M)
//   [64,80M)    x1 fp32(16M)
//   [80,88M)    nbuf/n2(8M)
//   [88,118M)   Qh/Kh/Vt(3x~10M)  -> later hbuf(32M) spans [88,120M)
// ---------------------------------------------------------------------------
extern "C" void kernel_launch(void* const* d_in, const int* in_sizes, int n_in,
                              void* d_out, int out_size, void* d_ws, size_t ws_size,
                              hipStream_t stream)
{
    const float* x   = (const float*)d_in[0];
    const float* ans = (const float*)d_in[1];
    const float* wq  = (const float*)d_in[2];
    const float* wk  = (const float*)d_in[3];
    const float* wv  = (const float*)d_in[4];
    const float* wo  = (const float*)d_in[5];
    const float* fns = (const float*)d_in[6];
    const float* wg  = (const float*)d_in[7];
    const float* wu  = (const float*)d_in[8];
    const float* wd  = (const float*)d_in[9];
    (void)in_sizes; (void)n_in; (void)out_size; (void)ws_size;

    char* ws = (char*)d_ws;
    const size_t MB = 1024 * 1024;
    bf16_t* wt_reg = (bf16_t*)(ws);             // 32 MB weight region
    bf16_t* qkv    = (bf16_t*)(ws + 32 * MB);   // 24 MB
    bf16_t* attnb  = (bf16_t*)(ws + 56 * MB);   // 8 MB
    bf16_t* gate   = (bf16_t*)(ws + 32 * MB);   // 32 MB (overlays dead qkv+attnb)
    float*  x1     = (float* )(ws + 64 * MB);   // 16 MB
    bf16_t* nbuf   = (bf16_t*)(ws + 80 * MB);   // 8 MB (also n2)
    bf16_t* Qh     = (bf16_t*)(ws + 88 * MB);   // 8.4 MB
    bf16_t* Kh     = (bf16_t*)(ws + 98 * MB);   // 8.4 MB
    bf16_t* Vt     = (bf16_t*)(ws + 108 * MB);  // 8.4 MB (transposed V)
    bf16_t* hbuf   = (bf16_t*)(ws + 88 * MB);   // 32 MB (overlays dead Qh/Kh/Vt)

    // ---- attention phase ----
    transpose_cvt<<<dim3(64, 64), 256, 0, stream>>>(wq, wt_reg,                             EMBED, EMBED);
    transpose_cvt<<<dim3(64, 64), 256, 0, stream>>>(wk, wt_reg + (size_t)EMBED * EMBED,     EMBED, EMBED);
    transpose_cvt<<<dim3(64, 64), 256, 0, stream>>>(wv, wt_reg + (size_t)2 * EMBED * EMBED, EMBED, EMBED);
    rmsnorm_bf16<<<NTOK, 256, 0, stream>>>(x, ans, nbuf);
    gemm_bt<0><<<dim3(16, 48), 256, 0, stream>>>(nbuf, wt_reg, qkv, nullptr, nullptr, NTOK, QKV_N, EMBED, EMBED);
    rope_transpose<<<256, 256, 0, stream>>>(qkv, Qh, Kh);
    transpose_v<<<dim3(32, 64), 256, 0, stream>>>(qkv, Vt);
    attn_sparse<<<1024, 256, 0, stream>>>(Qh, Kh, Vt, attnb);
    transpose_cvt<<<dim3(64, 64), 256, 0, stream>>>(wo, wt_reg, EMBED, EMBED);   // wqkv_t dead
    // attn-out GEMM: split-K=2 (512 blocks = 2/CU), x1 pre-init with residual x
    copy_f32<<<4096, 256, 0, stream>>>(x, x1);
    gemm_bt<3><<<dim3(16, 16, 2), 256, 0, stream>>>(attnb, wt_reg, x1, nullptr, nullptr, NTOK, EMBED, EMBED / 2, EMBED);

    // ---- MLP phase ----
    rmsnorm_bf16<<<NTOK, 256, 0, stream>>>(x1, fns, nbuf);                       // n2
    transpose_cvt<<<dim3(256, 64), 256, 0, stream>>>(wg, wt_reg, EMBED, MLP);    // wo_t dead
    gemm_bt<0><<<dim3(16, 64), 256, 0, stream>>>(nbuf, wt_reg, gate, nullptr, nullptr, NTOK, MLP, EMBED, EMBED);
    transpose_cvt<<<dim3(256, 64), 256, 0, stream>>>(wu, wt_reg, EMBED, MLP);    // wg_t dead
    gemm_bt<2><<<dim3(16, 64), 256, 0, stream>>>(nbuf, wt_reg, hbuf, nullptr, gate, NTOK, MLP, EMBED, EMBED);
    transpose_cvt<<<dim3(64, 256), 256, 0, stream>>>(wd, wt_reg, MLP, EMBED);    // wu_t dead
    // down GEMM: split-K=4 (1024 blocks = 4/CU), d_out pre-init with residual x1
    copy_f32<<<4096, 256, 0, stream>>>(x1, (float*)d_out);
    gemm_bt<3><<<dim3(16, 16, 4), 256, 0, stream>>>(hbuf, wt_reg, (float*)d_out, nullptr, nullptr, NTOK, EMBED, MLP / 4, MLP);
}

// Round 4
// 902.455 us; speedup vs baseline: 1.0889x; 1.0244x over previous
//
#include <hip/hip_runtime.h>
#include <math.h>

typedef __bf16 bf16_t;
typedef bf16_t bf16x8 __attribute__((ext_vector_type(8)));
typedef bf16_t bf16x2 __attribute__((ext_vector_type(2)));
typedef float f32x4 __attribute__((ext_vector_type(4)));

#define EMBED 2048
#define NHEADS 32
#define HDIM 64
#define MLP 8192
#define SEQ 1024
#define NTOK 2048      // B*S
#define QKV_N 6144

// async global->LDS, 16B per lane; LDS dest = wave-uniform base + lane*16
__device__ __forceinline__ void async_copy16(void* lds, const void* g) {
    __builtin_amdgcn_global_load_lds(
        (const __attribute__((address_space(1))) unsigned int*)g,
        (__attribute__((address_space(3))) unsigned int*)lds, 16, 0, 0);
}

// ---- DPP 16-lane (row) reductions: pure VALU, no LDS pipe ----
template<int CTRL>
__device__ __forceinline__ float dpp_f(float x) {
    return __int_as_float(__builtin_amdgcn_update_dpp(
        __float_as_int(x), __float_as_int(x), CTRL, 0xF, 0xF, false));
}
// row_ror:N = 0x120+N ; rotation folding gives ALL 16 lanes the result
__device__ __forceinline__ float rowmax16(float v) {
    v = fmaxf(v, dpp_f<0x121>(v));
    v = fmaxf(v, dpp_f<0x122>(v));
    v = fmaxf(v, dpp_f<0x124>(v));
    v = fmaxf(v, dpp_f<0x128>(v));
    return v;
}
__device__ __forceinline__ float rowsum16(float v) {
    v += dpp_f<0x121>(v);
    v += dpp_f<0x122>(v);
    v += dpp_f<0x124>(v);
    v += dpp_f<0x128>(v);
    return v;
}

// ---------------------------------------------------------------------------
// C = A(MxK,bf16) @ Bt(NxK,bf16)^T   (row stride LDK; K = per-split K-length,
// split z, k-range [z*K, z*K+K))
// EPI=0: bf16 store | EPI=1: fp32 store acc+Res | EPI=2: bf16 silu(Aux)*acc
// EPI=3: fp32 atomicAdd (split-K partial accumulate; Cout pre-initialized)
// 128x128 tile, BK=32, 4 waves, 16x16x32 bf16 MFMA.
// 2-phase double-buffered LDS (T3-min): next-tile global_load_lds issued
// BEFORE current ds_read+MFMA; single vmcnt(0)+barrier per K-step.
// XCD-chunked swizzle: each XCD owns a contiguous block-id range.
// ---------------------------------------------------------------------------
template<int EPI>
__global__ __launch_bounds__(256) void gemm_bt(
    const bf16_t* __restrict__ A, const bf16_t* __restrict__ Bt,
    void* __restrict__ Cout, const float* __restrict__ Res,
    const bf16_t* __restrict__ Aux,
    int M, int N, int K, int LDK)
{
    __shared__ __align__(16) bf16_t As[2][128 * 32];
    __shared__ __align__(16) bf16_t Bs[2][128 * 32];
    const int tid = threadIdx.x;
    const int wave = tid >> 6, lane = tid & 63;
    const int quad = lane >> 4, l15 = lane & 15;
    const int wr = wave >> 1, wc = wave & 1;

    // XCD-chunked swizzle (all grids are multiples of 8, gridDim.x == 16)
    const int nb  = gridDim.x * gridDim.y * gridDim.z;
    const int lid = blockIdx.x + gridDim.x * (blockIdx.y + gridDim.y * blockIdx.z);
    const int sw  = (lid & 7) * (nb >> 3) + (lid >> 3);
    const int bx  = sw & 15;
    const int rest = sw >> 4;
    const int by  = rest % gridDim.y;
    const int bz  = rest / gridDim.y;

    const int m0 = bx * 128, n0 = by * 128;
    const int srow = lane >> 2;
    const int scol = (lane & 3) * 8;

    const bf16_t* Ap = A  + (size_t)m0 * LDK + (size_t)bz * K;
    const bf16_t* Bp = Bt + (size_t)n0 * LDK + (size_t)bz * K;

    f32x4 acc[4][4] = {};

    auto stage = [&](int buf, int kk) {
#pragma unroll
        for (int s = 0; s < 2; ++s) {
            const int chunk = wave * 2 + s;
            const int row = chunk * 16 + srow;
            async_copy16((char*)As[buf] + chunk * 1024,
                         Ap + (size_t)row * LDK + kk + scol);
            async_copy16((char*)Bs[buf] + chunk * 1024,
                         Bp + (size_t)row * LDK + kk + scol);
        }
    };

    stage(0, 0);
    asm volatile("s_waitcnt vmcnt(0)" ::: "memory");
    __syncthreads();

    const int nsteps = K >> 5;
    int cur = 0;
    for (int t = 0; t < nsteps; ++t) {
        if (t + 1 < nsteps) stage(cur ^ 1, (t + 1) * 32);   // prefetch next tile

        bf16x8 af[4], bfr[4];
#pragma unroll
        for (int i = 0; i < 4; ++i) {
            af[i]  = *(const bf16x8*)((const char*)As[cur] + (wr * 64 + i * 16 + l15) * 64 + quad * 16);
            bfr[i] = *(const bf16x8*)((const char*)Bs[cur] + (wc * 64 + i * 16 + l15) * 64 + quad * 16);
        }
#pragma unroll
        for (int i = 0; i < 4; ++i)
#pragma unroll
            for (int j = 0; j < 4; ++j)
                acc[i][j] = __builtin_amdgcn_mfma_f32_16x16x32_bf16(af[i], bfr[j], acc[i][j], 0, 0, 0);

        if (t + 1 < nsteps) {
            asm volatile("s_waitcnt vmcnt(0)" ::: "memory");
            __syncthreads();
        }
        cur ^= 1;
    }

#pragma unroll
    for (int i = 0; i < 4; ++i) {
#pragma unroll
        for (int j = 0; j < 4; ++j) {
#pragma unroll
            for (int r = 0; r < 4; ++r) {
                const int row = m0 + wr * 64 + i * 16 + quad * 4 + r;
                const int col = n0 + wc * 64 + j * 16 + l15;
                const size_t idx = (size_t)row * N + col;
                if (EPI == 0) {
                    ((bf16_t*)Cout)[idx] = (bf16_t)acc[i][j][r];
                } else if (EPI == 1) {
                    ((float*)Cout)[idx] = Res[idx] + acc[i][j][r];
                } else if (EPI == 2) {
                    const float g = (float)Aux[idx];
                    const float s = g / (1.0f + __expf(-g));
                    ((bf16_t*)Cout)[idx] = (bf16_t)(s * acc[i][j][r]);
                } else {
                    // split-K partial: native fp32 atomic add (device scope)
                    unsafeAtomicAdd(&((float*)Cout)[idx], acc[i][j][r]);
                }
            }
        }
    }
}

// ---------------------------------------------------------------------------
// fp32 float4 copy (split-K output init with residual)
// ---------------------------------------------------------------------------
__global__ __launch_bounds__(256) void copy_f32(
    const float* __restrict__ src, float* __restrict__ dst)
{
    const int i = blockIdx.x * 256 + threadIdx.x;
    ((float4*)dst)[i] = ((const float4*)src)[i];
}

// ---------------------------------------------------------------------------
// W (KxN fp32) -> Wt (NxK bf16), 32x32 LDS tiles
// ---------------------------------------------------------------------------
__global__ __launch_bounds__(256) void transpose_cvt(
    const float* __restrict__ src, bf16_t* __restrict__ dst, int K, int N)
{
    __shared__ float tile[32][33];
    const int tx = threadIdx.x & 31, ty = threadIdx.x >> 5;
    const int n0 = blockIdx.x * 32, k0 = blockIdx.y * 32;
#pragma unroll
    for (int i = 0; i < 4; ++i)
        tile[ty + 8 * i][tx] = src[(size_t)(k0 + ty + 8 * i) * N + n0 + tx];
    __syncthreads();
#pragma unroll
    for (int i = 0; i < 4; ++i)
        dst[(size_t)(n0 + ty + 8 * i) * K + k0 + tx] = (bf16_t)tile[tx][ty + 8 * i];
}

// ---------------------------------------------------------------------------
// RMSNorm: fp32 row (2048) -> bf16 row
// ---------------------------------------------------------------------------
__global__ __launch_bounds__(256) void rmsnorm_bf16(
    const float* __restrict__ x, const float* __restrict__ g, bf16_t* __restrict__ out)
{
    const int row = blockIdx.x;
    const int tid = threadIdx.x;
    const float* xr = x + (size_t)row * EMBED + tid * 8;
    const float4 a = *(const float4*)xr;
    const float4 b = *(const float4*)(xr + 4);
    float ss = a.x * a.x + a.y * a.y + a.z * a.z + a.w * a.w
             + b.x * b.x + b.y * b.y + b.z * b.z + b.w * b.w;
#pragma unroll
    for (int off = 1; off < 64; off <<= 1) ss += __shfl_xor(ss, off);
    __shared__ float red[4];
    if ((tid & 63) == 0) red[tid >> 6] = ss;
    __syncthreads();
    const float rs = rsqrtf((red[0] + red[1] + red[2] + red[3]) * (1.0f / EMBED) + 1e-5f);
    const float* gr = g + tid * 8;
    const float xv[8] = {a.x, a.y, a.z, a.w, b.x, b.y, b.z, b.w};
    bf16x8 o;
#pragma unroll
    for (int e = 0; e < 8; ++e) o[e] = (bf16_t)(xv[e] * rs * gr[e]);
    *(bf16x8*)(out + (size_t)row * EMBED + tid * 8) = o;
}

// ---------------------------------------------------------------------------
// qkv [tok][6144] -> head-major Qh,Kh [(b*32+h)][s][64], RoPE.
// Q additionally scaled by 0.125 (exact) so attention skips the scale.
// ---------------------------------------------------------------------------
__global__ __launch_bounds__(256) void rope_transpose(
    const bf16_t* __restrict__ qkv, bf16_t* __restrict__ Qh, bf16_t* __restrict__ Kh)
{
    const int id = blockIdx.x * 256 + threadIdx.x;   // 0..65535
    const int tok = id >> 5;
    const int h = id & 31;
    const int s = tok & (SEQ - 1);
    const int bh = (tok >> 10) * NHEADS + h;
    const size_t dst = ((size_t)bh * SEQ + s) * HDIM;

    const bf16_t* q = qkv + (size_t)tok * QKV_N + h * HDIM;
    const bf16_t* k = q + EMBED;

    const bf16x2* qp = (const bf16x2*)q;
    const bf16x2* kp = (const bf16x2*)k;
    bf16x2* qo = (bf16x2*)(Qh + dst);
    bf16x2* ko = (bf16x2*)(Kh + dst);
    for (int i = 0; i < 32; ++i) {
        // 1/theta^(i/32) = exp2(-i*log2(5e5)/32)
        const float inv = exp2f((float)i * -0.59161151779f);
        const float ang = (float)s * inv;
        float sn, cs;
        sincosf(ang, &sn, &cs);
        bf16x2 qv = qp[i], kv = kp[i];
        const float q0 = (float)qv[0], q1 = (float)qv[1];
        const float k0 = (float)kv[0], k1 = (float)kv[1];
        qv[0] = (bf16_t)((q0 * cs - q1 * sn) * 0.125f);
        qv[1] = (bf16_t)((q0 * sn + q1 * cs) * 0.125f);
        kv[0] = (bf16_t)(k0 * cs - k1 * sn);
        kv[1] = (bf16_t)(k0 * sn + k1 * cs);
        qo[i] = qv; ko[i] = kv;
    }
}

// ---------------------------------------------------------------------------
// V transpose: qkv v-section -> Vt[(b*32+h)][dim][seq]
// grid (32 s-tiles, 64 bh), 256 threads
// ---------------------------------------------------------------------------
__global__ __launch_bounds__(256) void transpose_v(
    const bf16_t* __restrict__ qkv, bf16_t* __restrict__ Vt)
{
    __shared__ bf16_t tile[32][66];
    const int st = blockIdx.x;       // seq tile (32 rows)
    const int bh = blockIdx.y;
    const int b = bh >> 5, h = bh & 31;
    const int tid = threadIdx.x;

    const int d = tid & 63, sr = tid >> 6;
    const bf16_t* src = qkv + (size_t)(b * SEQ + st * 32) * QKV_N + 2 * EMBED + h * HDIM;
#pragma unroll
    for (int i = 0; i < 8; ++i) {
        const int s = i * 4 + sr;
        tile[s][d] = src[(size_t)s * QKV_N + d];
    }
    __syncthreads();
    const int s2 = tid & 31, dr = tid >> 5;
    bf16_t* dstp = Vt + (size_t)bh * HDIM * SEQ + st * 32;
#pragma unroll
    for (int i = 0; i < 8; ++i) {
        const int dd = i * 8 + dr;
        dstp[(size_t)dd * SEQ + s2] = tile[s2][dd];
    }
}

// ---------------------------------------------------------------------------
// Tile-sparse attention v5. 1-D grid of 1024, XCD-colocating decode:
//   x = id&7 (XCD), j = id>>3; qg = j&15, hb = (j>>4)*8 + x
// Wave->qt map {qg, 31-qg, 32+qg, 63-qg}: per-block pass-1 work constant.
// ---------------------------------------------------------------------------
__global__ __launch_bounds__(256, 4) void attn_sparse(
    const bf16_t* __restrict__ Qh, const bf16_t* __restrict__ Kh,
    const bf16_t* __restrict__ Vt, bf16_t* __restrict__ attn)
{
    const int id = blockIdx.x;
    const int xcd = id & 7;
    const int j = id >> 3;
    const int qg = j & 15;           // 0..15
    const int hb = (j >> 4) * 8 + xcd;
    const int h = hb & 31;
    const int b = hb >> 5;
    const int tid  = threadIdx.x;
    const int wave = tid >> 6, lane = tid & 63;
    const int quad = lane >> 4, l15 = lane & 15;
    // balanced qt: {qg, 31-qg, 32+qg, 63-qg} -> block work sum constant
    const int qt = (wave & 1) ? (wave * 16 + 15 - qg) : (wave * 16 + qg);

    __shared__ __align__(16) float  tilemax[4][16][68];
    __shared__ __align__(16) bf16_t Plds[4][16][40];
    __shared__ unsigned long long qmask[4][16];

    const size_t hoff = (size_t)(b * NHEADS + h) * SEQ * HDIM;
    const bf16_t* Qb  = Qh + hoff;
    const bf16_t* Kb  = Kh + hoff;
    const bf16_t* Vtb = Vt + hoff;   // [64][1024]

    const bf16_t* qrow = Qb + (size_t)(qt * 16 + l15) * HDIM;
    const bf16x8 qf0 = *(const bf16x8*)(qrow + quad * 8);
    const bf16x8 qf1 = *(const bf16x8*)(qrow + 32 + quad * 8);

    // ---- pass 1: tile maxima (DPP reduce, 1-ahead prefetch) ----
    const bf16_t* kbase = Kb + (size_t)l15 * HDIM + quad * 8;
    bf16x8 kc0 = *(const bf16x8*)(kbase);
    bf16x8 kc1 = *(const bf16x8*)(kbase + 32);
    for (int t = 0; t <= qt; ++t) {
        const bf16_t* knp = kbase + (size_t)((t < qt) ? t + 1 : t) * (16 * HDIM);
        const bf16x8 kn0 = *(const bf16x8*)(knp);
        const bf16x8 kn1 = *(const bf16x8*)(knp + 32);
        f32x4 sc = {0.f, 0.f, 0.f, 0.f};
        sc = __builtin_amdgcn_mfma_f32_16x16x32_bf16(qf0, kc0, sc, 0, 0, 0);
        sc = __builtin_amdgcn_mfma_f32_16x16x32_bf16(qf1, kc1, sc, 0, 0, 0);
#pragma unroll
        for (int r = 0; r < 4; ++r) {
            const int qr = quad * 4 + r;
            float v = (t == qt && l15 > qr) ? -3.0e38f : sc[r];
            v = rowmax16(v);
            if (l15 == 0) tilemax[wave][qr][t] = v;
        }
        kc0 = kn0; kc1 = kn1;
    }
    asm volatile("s_waitcnt lgkmcnt(0)" ::: "memory");   // in-wave DS drain

    // ---- selection: top-12 (strict >, earliest on ties) + own ----
    if (lane < 16) {
        unsigned long long m = 0;
        const int cnt = qt + 1;
        if (cnt <= 12) {
            m = (1ull << cnt) - 1ull;
        } else {
            const float* tmrow = &tilemax[wave][lane][0];
            const int c4 = qt >> 2;
            for (int it = 0; it < 12; ++it) {
                float best = -3.9e38f; int bi = 0;
                for (int c = 0; c <= c4; ++c) {
                    const float4 v4 = *(const float4*)(tmrow + c * 4);
                    const int tb = c * 4;
                    if (tb + 0 <= qt && !((m >> (tb + 0)) & 1ull) && v4.x > best) { best = v4.x; bi = tb + 0; }
                    if (tb + 1 <= qt && !((m >> (tb + 1)) & 1ull) && v4.y > best) { best = v4.y; bi = tb + 1; }
                    if (tb + 2 <= qt && !((m >> (tb + 2)) & 1ull) && v4.z > best) { best = v4.z; bi = tb + 2; }
                    if (tb + 3 <= qt && !((m >> (tb + 3)) & 1ull) && v4.w > best) { best = v4.w; bi = tb + 3; }
                }
                m |= 1ull << bi;
            }
        }
        m |= 1ull << qt;
        qmask[wave][lane] = m;
    }
    asm volatile("s_waitcnt lgkmcnt(0)" ::: "memory");

    unsigned long long un = 0;
#pragma unroll
    for (int i = 0; i < 16; ++i) un |= qmask[wave][i];
    unsigned long long myrow[4];
#pragma unroll
    for (int r = 0; r < 4; ++r) myrow[r] = qmask[wave][quad * 4 + r];

    float m_run[4], l_run[4];
#pragma unroll
    for (int r = 0; r < 4; ++r) { m_run[r] = -3.0e38f; l_run[r] = 0.f; }
    f32x4 o[4] = {};   // o[jb][r] = D[quad*4+r][jb*16+l15]

    // ---- pass 2: selected tiles in pairs, MFMA PV ----
    unsigned long long sel = un;
    while (sel) {
        const int t0 = (int)__builtin_ctzll(sel); sel &= sel - 1ull;
        int t1 = -1;
        if (sel) { t1 = (int)__builtin_ctzll(sel); sel &= sel - 1ull; }
        const int t1e = (t1 >= 0) ? t1 : t0;

        const bf16_t* kr0 = Kb + (size_t)(t0 * 16 + l15) * HDIM + quad * 8;
        const bf16x8 k00 = *(const bf16x8*)(kr0);
        const bf16x8 k01 = *(const bf16x8*)(kr0 + 32);
        const bf16_t* kr1 = Kb + (size_t)(t1e * 16 + l15) * HDIM + quad * 8;
        const bf16x8 k10 = *(const bf16x8*)(kr1);
        const bf16x8 k11 = *(const bf16x8*)(kr1 + 32);

        // B-frags from global V^T (keys: quad<2 -> t0, quad>=2 -> t1e)
        const int colb = ((quad < 2) ? t0 : t1e) * 16 + (quad & 1) * 8;
        bf16x8 vf[4];
#pragma unroll
        for (int jb = 0; jb < 4; ++jb)
            vf[jb] = *(const bf16x8*)(Vtb + (size_t)(jb * 16 + l15) * SEQ + colb);

        f32x4 s0 = {0.f, 0.f, 0.f, 0.f}, s1 = {0.f, 0.f, 0.f, 0.f};
        s0 = __builtin_amdgcn_mfma_f32_16x16x32_bf16(qf0, k00, s0, 0, 0, 0);
        s0 = __builtin_amdgcn_mfma_f32_16x16x32_bf16(qf1, k01, s0, 0, 0, 0);
        s1 = __builtin_amdgcn_mfma_f32_16x16x32_bf16(qf0, k10, s1, 0, 0, 0);
        s1 = __builtin_amdgcn_mfma_f32_16x16x32_bf16(qf1, k11, s1, 0, 0, 0);

#pragma unroll
        for (int r = 0; r < 4; ++r) {
            const int qr = quad * 4 + r;
            const bool ok0 = ((myrow[r] >> t0) & 1ull) && (t0 < qt || l15 <= qr);
            const bool ok1 = (t1 >= 0) && ((myrow[r] >> t1) & 1ull) && (t1 < qt || l15 <= qr);
            const float sv0 = ok0 ? s0[r] : -3.0e38f;
            const float sv1 = ok1 ? s1[r] : -3.0e38f;
            const float mt = rowmax16(fmaxf(sv0, sv1));
            const float mn = fmaxf(m_run[r], mt);
            const float al = __expf(m_run[r] - mn);
            const float p0 = ok0 ? __expf(sv0 - mn) : 0.f;
            const float p1 = ok1 ? __expf(sv1 - mn) : 0.f;
            const float rsum = rowsum16(p0 + p1);
            l_run[r] = l_run[r] * al + rsum;
            m_run[r] = mn;
            Plds[wave][qr][l15]      = (bf16_t)p0;
            Plds[wave][qr][16 + l15] = (bf16_t)p1;
#pragma unroll
            for (int jb = 0; jb < 4; ++jb) o[jb][r] *= al;
        }
        asm volatile("s_waitcnt lgkmcnt(0)" ::: "memory");

        const bf16x8 pa = *(const bf16x8*)&Plds[wave][l15][quad * 8];
#pragma unroll
        for (int jb = 0; jb < 4; ++jb)
            o[jb] = __builtin_amdgcn_mfma_f32_16x16x32_bf16(pa, vf[jb], o[jb], 0, 0, 0);
    }

    // ---- epilogue: normalize, store ----
    const int tok0 = b * SEQ + qt * 16;
#pragma unroll
    for (int r = 0; r < 4; ++r) {
        const int qr = quad * 4 + r;
        const float inv = 1.0f / l_run[r];
        bf16_t* op = attn + (size_t)(tok0 + qr) * EMBED + h * HDIM + l15;
#pragma unroll
        for (int jb = 0; jb < 4; ++jb)
            op[jb * 16] = (bf16_t)(o[jb][r] * inv);
    }
}

// ---------------------------------------------------------------------------
// Workspace layout (120 MB peak, lifetime-overlaid):
//   [0,32M)     Wt region: wqkv_t(24M)/wo_t(8M)/wg_t(32M)/wu_t(32M)/wd_t(32M)
//   [32,56M)    qkv(24M)          -> later gate(32M) spans [32,64M)
//   [56,64M)    attnb(8M)
//   [64,80M)    x1 fp32(16M)
//   [80,88M)    nbuf/n2(8M)
//   [88,118M)   Qh/Kh/Vt(3x~10M)  -> later hbuf(32M) spans [88,120M)
// ---------------------------------------------------------------------------
extern "C" void kernel_launch(void* const* d_in, const int* in_sizes, int n_in,
                              void* d_out, int out_size, void* d_ws, size_t ws_size,
                              hipStream_t stream)
{
    const float* x   = (const float*)d_in[0];
    const float* ans = (const float*)d_in[1];
    const float* wq  = (const float*)d_in[2];
    const float* wk  = (const float*)d_in[3];
    const float* wv  = (const float*)d_in[4];
    const float* wo  = (const float*)d_in[5];
    const float* fns = (const float*)d_in[6];
    const float* wg  = (const float*)d_in[7];
    const float* wu  = (const float*)d_in[8];
    const float* wd  = (const float*)d_in[9];
    (void)in_sizes; (void)n_in; (void)out_size; (void)ws_size;

    char* ws = (char*)d_ws;
    const size_t MB = 1024 * 1024;
    bf16_t* wt_reg = (bf16_t*)(ws);             // 32 MB weight region
    bf16_t* qkv    = (bf16_t*)(ws + 32 * MB);   // 24 MB
    bf16_t* attnb  = (bf16_t*)(ws + 56 * MB);   // 8 MB
    bf16_t* gate   = (bf16_t*)(ws + 32 * MB);   // 32 MB (overlays dead qkv+attnb)
    float*  x1     = (float* )(ws + 64 * MB);   // 16 MB
    bf16_t* nbuf   = (bf16_t*)(ws + 80 * MB);   // 8 MB (also n2)
    bf16_t* Qh     = (bf16_t*)(ws + 88 * MB);   // 8.4 MB
    bf16_t* Kh     = (bf16_t*)(ws + 98 * MB);   // 8.4 MB
    bf16_t* Vt     = (bf16_t*)(ws + 108 * MB);  // 8.4 MB (transposed V)
    bf16_t* hbuf   = (bf16_t*)(ws + 88 * MB);   // 32 MB (overlays dead Qh/Kh/Vt)

    // ---- attention phase ----
    transpose_cvt<<<dim3(64, 64), 256, 0, stream>>>(wq, wt_reg,                             EMBED, EMBED);
    transpose_cvt<<<dim3(64, 64), 256, 0, stream>>>(wk, wt_reg + (size_t)EMBED * EMBED,     EMBED, EMBED);
    transpose_cvt<<<dim3(64, 64), 256, 0, stream>>>(wv, wt_reg + (size_t)2 * EMBED * EMBED, EMBED, EMBED);
    rmsnorm_bf16<<<NTOK, 256, 0, stream>>>(x, ans, nbuf);
    gemm_bt<0><<<dim3(16, 48), 256, 0, stream>>>(nbuf, wt_reg, qkv, nullptr, nullptr, NTOK, QKV_N, EMBED, EMBED);
    rope_transpose<<<256, 256, 0, stream>>>(qkv, Qh, Kh);
    transpose_v<<<dim3(32, 64), 256, 0, stream>>>(qkv, Vt);
    attn_sparse<<<1024, 256, 0, stream>>>(Qh, Kh, Vt, attnb);
    transpose_cvt<<<dim3(64, 64), 256, 0, stream>>>(wo, wt_reg, EMBED, EMBED);   // wqkv_t dead
    // attn-out GEMM: split-K=2, x1 pre-init with residual x
    copy_f32<<<4096, 256, 0, stream>>>(x, x1);
    gemm_bt<3><<<dim3(16, 16, 2), 256, 0, stream>>>(attnb, wt_reg, x1, nullptr, nullptr, NTOK, EMBED, EMBED / 2, EMBED);

    // ---- MLP phase ----
    rmsnorm_bf16<<<NTOK, 256, 0, stream>>>(x1, fns, nbuf);                       // n2
    transpose_cvt<<<dim3(256, 64), 256, 0, stream>>>(wg, wt_reg, EMBED, MLP);    // wo_t dead
    gemm_bt<0><<<dim3(16, 64), 256, 0, stream>>>(nbuf, wt_reg, gate, nullptr, nullptr, NTOK, MLP, EMBED, EMBED);
    transpose_cvt<<<dim3(256, 64), 256, 0, stream>>>(wu, wt_reg, EMBED, MLP);    // wg_t dead
    gemm_bt<2><<<dim3(16, 64), 256, 0, stream>>>(nbuf, wt_reg, hbuf, nullptr, gate, NTOK, MLP, EMBED, EMBED);
    transpose_cvt<<<dim3(64, 256), 256, 0, stream>>>(wd, wt_reg, MLP, EMBED);    // wu_t dead
    // down GEMM: split-K=4, d_out pre-init with residual x1
    copy_f32<<<4096, 256, 0, stream>>>(x1, (float*)d_out);
    gemm_bt<3><<<dim3(16, 16, 4), 256, 0, stream>>>(hbuf, wt_reg, (float*)d_out, nullptr, nullptr, NTOK, EMBED, MLP / 4, MLP);
}